// Round 13
// baseline (582.307 us; speedup 1.0000x reference)
//
#include <hip/hip_runtime.h>
#include <hip/hip_fp16.h>
#include <math.h>

#define ALPHA_C 0.6f

typedef _Float16 f16;
typedef f16 f16x8 __attribute__((ext_vector_type(8)));
typedef float f32x4 __attribute__((ext_vector_type(4)));

// ---------------------------------------------------------------------------
// x fp32 -> fp16, pure streaming.
// ---------------------------------------------------------------------------
__global__ void f32_to_f16_kernel(const float* __restrict__ in, f16* __restrict__ out, int n8) {
    int i = blockIdx.x * blockDim.x + threadIdx.x;
    if (i >= n8) return;
    float4 a = ((const float4*)in)[2 * i];
    float4 b = ((const float4*)in)[2 * i + 1];
    f16x8 o;
    o[0] = (f16)a.x; o[1] = (f16)a.y; o[2] = (f16)a.z; o[3] = (f16)a.w;
    o[4] = (f16)b.x; o[5] = (f16)b.y; o[6] = (f16)b.z; o[7] = (f16)b.w;
    ((f16x8*)out)[i] = o;
}

// ---------------------------------------------------------------------------
// Edge-index dtype detection (int64 reference vs int32 harness doc).
// ---------------------------------------------------------------------------
__global__ void detect_idx_kernel(const void* __restrict__ ei, int* __restrict__ flag,
                                  int E, int N) {
    int i = blockIdx.x * blockDim.x + threadIdx.x;
    if (i >= E) return;
    long long v = ((const long long*)ei)[i];
    if (v < 0 || v >= (long long)N) *flag = 1;  // -> data is int32
}

// convert to int32 AND count destination degrees in one pass
__global__ void convert_count_kernel(const void* __restrict__ ei, const int* __restrict__ flag,
                                     int* __restrict__ out, int* __restrict__ cnt,
                                     int E, int n2e) {
    int i = blockIdx.x * blockDim.x + threadIdx.x;
    if (i >= n2e) return;
    int v;
    if (*flag == 0)
        v = (int)((const long long*)ei)[i];   // int64 source
    else
        v = ((const int*)ei)[i];              // already int32
    out[i] = v;
    if (i >= E) atomicAdd(&cnt[v], 1);        // dst half
}

// --- hierarchical exclusive scan: reduce (+dinv) -> top scan -> fill -------
__global__ void block_reduce_kernel(const int* __restrict__ cnt, int* __restrict__ bsum,
                                    float* __restrict__ dinv, int n) {
    __shared__ int s[256];
    int tid = threadIdx.x;
    int i = blockIdx.x * 256 + tid;
    int v = (i < n) ? cnt[i] : 0;
    if (i < n) dinv[i] = rsqrtf((float)v + 1.0f);   // +1 self-loop
    s[tid] = v;
    __syncthreads();
    for (int o = 128; o > 0; o >>= 1) {
        if (tid < o) s[tid] += s[tid + o];
        __syncthreads();
    }
    if (tid == 0) bsum[blockIdx.x] = s[0];
}

__global__ void scan_top_kernel(int* __restrict__ bsum, int nb) {
    __shared__ int s[1024];
    int tid = threadIdx.x;
    int v = (tid < nb) ? bsum[tid] : 0;
    s[tid] = v;
    __syncthreads();
    for (int o = 1; o < 1024; o <<= 1) {
        int t = (tid >= o) ? s[tid - o] : 0;
        __syncthreads();
        s[tid] += t;
        __syncthreads();
    }
    if (tid < nb) bsum[tid] = s[tid] - v;   // exclusive
}

// row_off build; ALSO seeds gcur[b] = row_off[64*b] (bucket write cursors)
__global__ void scan_fill_kernel(const int* __restrict__ cnt, const int* __restrict__ bsum,
                                 int* __restrict__ row_off, int* __restrict__ gcur, int n) {
    __shared__ int s[256];
    int tid = threadIdx.x;
    int i = blockIdx.x * 256 + tid;
    int v = (i < n) ? cnt[i] : 0;
    s[tid] = v;
    __syncthreads();
    for (int o = 1; o < 256; o <<= 1) {
        int t = (tid >= o) ? s[tid - o] : 0;
        __syncthreads();
        s[tid] += t;
        __syncthreads();
    }
    int base = bsum[blockIdx.x];
    if (i < n) {
        int ro = base + s[tid] - v;
        row_off[i] = ro;
        if ((i & 63) == 0) gcur[i >> 6] = ro;
    }
    if (i == n - 1) row_off[n] = base + s[tid];
}

// ---------------------------------------------------------------------------
// Bucket scatter: group edges by dst>>6 into ebuf (pair = src | dst<<16).
// Per-block LDS compaction; copy-out is wave-coalesced per bucket run, so
// HBM writes are line-efficient (vs 64B per 4B random store in old fill).
// CHUNK=8192 edges/block; NB <= 1024 buckets (N <= 65536).
// ---------------------------------------------------------------------------
__global__ __launch_bounds__(256) void bucket_scatter_kernel(
    const int* __restrict__ src, const int* __restrict__ dst,
    int* __restrict__ gcur, unsigned int* __restrict__ ebuf, int E, int NB) {
    __shared__ int hist[1024];
    __shared__ int loff[1024];    // inclusive scan of hist
    __shared__ int lbase[1024];   // global base per bucket (this block's run)
    __shared__ int lcur[1024];
    __shared__ unsigned int lbuf[8192];
    int tid = threadIdx.x;
    int e0 = blockIdx.x * 8192;
    int ecnt = E - e0; if (ecnt > 8192) ecnt = 8192;

    for (int i = tid; i < 1024; i += 256) { hist[i] = 0; lcur[i] = 0; }
    __syncthreads();
    for (int i = tid; i < ecnt; i += 256)
        atomicAdd(&hist[(unsigned)dst[e0 + i] >> 6], 1);
    __syncthreads();
    for (int i = tid; i < 1024; i += 256) loff[i] = hist[i];
    __syncthreads();
    for (int o = 1; o < 1024; o <<= 1) {
        int v[4];
#pragma unroll
        for (int r = 0; r < 4; ++r) { int i = tid + r * 256; v[r] = (i >= o) ? loff[i - o] : 0; }
        __syncthreads();
#pragma unroll
        for (int r = 0; r < 4; ++r) { int i = tid + r * 256; loff[i] += v[r]; }
        __syncthreads();
    }
    for (int b = tid; b < NB; b += 256) {
        int h = hist[b];
        lbase[b] = h ? atomicAdd(&gcur[b], h) : 0;
    }
    __syncthreads();
    for (int i = tid; i < ecnt; i += 256) {
        int d = dst[e0 + i], s = src[e0 + i];
        int b = (unsigned)d >> 6;
        int p = atomicAdd(&lcur[b], 1);
        lbuf[loff[b] - hist[b] + p] = (unsigned)s | ((unsigned)d << 16);
    }
    __syncthreads();
    int wave = tid >> 6, lane = tid & 63;
    for (int b = wave; b < NB; b += 4) {
        int h = hist[b];
        int lo = loff[b] - h;
        int gb = lbase[b];
        for (int j = lane; j < h; j += 64) ebuf[gb + j] = lbuf[lo + j];
    }
}

// ---------------------------------------------------------------------------
// CSR finalize: per 64-node bucket, place entries at exact CSR positions in
// LDS, then stream to csre with fully-coalesced stores. Fallback to direct
// scatter if a bucket exceeds LDS capacity (adversarial degree only).
// csre entry = src:u16 | fp16(w)<<16.
// ---------------------------------------------------------------------------
__global__ __launch_bounds__(256) void csr_finalize_kernel(
    const unsigned int* __restrict__ ebuf, const int* __restrict__ row_off,
    const float* __restrict__ dinv, unsigned int* __restrict__ csre, int N) {
    __shared__ int lcur[64];
    __shared__ unsigned int lbuf[2048];
    int b = blockIdx.x;
    int n0 = b * 64;
    int n1 = n0 + 64; if (n1 > N) n1 = N;
    int base = row_off[n0];
    int cnt = row_off[n1] - base;
    int tid = threadIdx.x;
    if (tid < 64) lcur[tid] = 0;
    __syncthreads();
    bool fits = (cnt <= 2048);
    for (int i = tid; i < cnt; i += 256) {
        unsigned int pr = ebuf[base + i];
        int s = pr & 0xFFFF;
        int d = pr >> 16;
        float w = dinv[s] * dinv[d];
        unsigned int entry = (unsigned)s |
                             ((unsigned)__half_as_ushort(__float2half(w)) << 16);
        int rel = row_off[d] - base;
        int p = atomicAdd(&lcur[d - n0], 1);
        if (fits) lbuf[rel + p] = entry;
        else      csre[base + rel + p] = entry;
    }
    __syncthreads();
    if (fits)
        for (int i = tid; i < cnt; i += 256) csre[base + i] = lbuf[i];
}

// ---------------------------------------------------------------------------
// Weight prep: all six W[K][N] fp32 -> Wt[N][K] fp16, one dispatch.
// ---------------------------------------------------------------------------
__global__ void prep_all_w_kernel(
    const float* __restrict__ Wc1, const float* __restrict__ Wl1,
    const float* __restrict__ Wc2, const float* __restrict__ Wl2,
    const float* __restrict__ Wc3, const float* __restrict__ Wl3,
    f16* __restrict__ w1c, f16* __restrict__ w1l,
    f16* __restrict__ w2c, f16* __restrict__ w2l,
    f16* __restrict__ w3c, f16* __restrict__ w3l) {
    int i = blockIdx.x * blockDim.x + threadIdx.x;
    const float* W; f16* O; int K, Nn, base;
    if      (i <  32768) { W = Wc1; O = w1c; K = 256; Nn = 128; base = i; }
    else if (i <  65536) { W = Wl1; O = w1l; K = 256; Nn = 128; base = i - 32768; }
    else if (i <  81920) { W = Wc2; O = w2c; K = 128; Nn = 128; base = i - 65536; }
    else if (i <  98304) { W = Wl2; O = w2l; K = 128; Nn = 128; base = i - 81920; }
    else if (i < 106496) { W = Wc3; O = w3c; K = 128; Nn = 64;  base = i - 98304; }
    else if (i < 114688) { W = Wl3; O = w3l; K = 128; Nn = 64;  base = i - 106496; }
    else return;
    int k = base / Nn, n = base - k * Nn;
    O[(size_t)n * K + k] = (f16)W[base];
}

// ---------------------------------------------------------------------------
// MFMA GEMM v6 (R12): A row-share hoisted to registers; W in fragment-layout
// LDS (conflict-free contiguous 1KB reads); BM=64, SPLIT column-split.
// AMODE: 0 = A f16 [M][K]; 2 = A = elu(A0+A1), both f16.
// mfma_f32_16x16x32_f16; C/D: col=lane&15, row=(lane>>4)*4+reg (m89/m91).
// ---------------------------------------------------------------------------
template <int K, int NH, int AMODE, int SPLIT>
__global__ __launch_bounds__(256) void gemm2_kernel(
    const void* __restrict__ A0v, const void* __restrict__ A1v,
    const f16* __restrict__ WtA, const f16* __restrict__ WtB,
    const float* __restrict__ biasA, const float* __restrict__ biasB,
    f16* __restrict__ CA, f16* __restrict__ CB, int M) {
    constexpr int NT = 2 * NH / 16;
    constexpr int NTS = NT / SPLIT;
    constexpr int KS = K / 32;
    __shared__ f16 Wlds[NTS * 1024];

    int tid = threadIdx.x;
    int wv = tid >> 6, lane = tid & 63;
    int lr = lane & 15, lhi = lane >> 4;
    int m0 = blockIdx.x * 64;
    int tg0 = blockIdx.y * NTS;

    f32x4 acc[NTS];
#pragma unroll
    for (int t = 0; t < NTS; ++t) acc[t] = (f32x4){0.f, 0.f, 0.f, 0.f};

    int arow = m0 + wv * 16 + lr;
    int arow_c = arow < M ? arow : M - 1;
    size_t aoff = (size_t)arow_c * K + lhi * 8;

    f16x8 a[KS];
#pragma unroll
    for (int j = 0; j < KS; ++j) {
        size_t idx = aoff + j * 32;
        if constexpr (AMODE == 0) {
            a[j] = *(const f16x8*)((const f16*)A0v + idx);
        } else {
            f16x8 u0 = *(const f16x8*)((const f16*)A0v + idx);
            f16x8 u1 = *(const f16x8*)((const f16*)A1v + idx);
            f16x8 v;
#pragma unroll
            for (int jj = 0; jj < 8; ++jj) {
                float tt = (float)u0[jj] + (float)u1[jj];
                v[jj] = (f16)(tt > 0.f ? tt : expm1f(tt));
            }
            a[j] = v;
        }
    }

#pragma unroll
    for (int k0 = 0; k0 < K; k0 += 64) {
        for (int c = tid; c < NTS * 128; c += 256) {
            int tl = c >> 7;
            int rem = c & 127;
            int ks = rem >> 6, kh = (rem >> 4) & 3, r = rem & 15;
            int tg = tg0 + tl;
            int nloc = (tg < NT / 2) ? tg : tg - NT / 2;
            const f16* srcp = ((tg < NT / 2) ? WtA : WtB)
                              + (size_t)(nloc * 16 + r) * K + k0 + ks * 32 + kh * 8;
            *(f16x8*)&Wlds[(size_t)c * 8] = *(const f16x8*)srcp;
        }
        __syncthreads();

#pragma unroll
        for (int s2 = 0; s2 < 2; ++s2) {
#pragma unroll
            for (int t = 0; t < NTS; ++t) {
                f16x8 b = *(const f16x8*)&Wlds[(size_t)(t * 128 + s2 * 64 + lane) * 8];
                acc[t] = __builtin_amdgcn_mfma_f32_16x16x32_f16(a[k0 / 32 + s2], b, acc[t], 0, 0, 0);
            }
        }
        __syncthreads();
    }

    int rbase = m0 + wv * 16 + lhi * 4;
#pragma unroll
    for (int t = 0; t < NTS; ++t) {
        int tg = tg0 + t;
        bool isA = (tg < NT / 2);
        int colg = (isA ? tg : tg - NT / 2) * 16 + lr;
        f16* outp = isA ? CA : CB;
        float bv = (isA ? biasA : biasB)[colg];
#pragma unroll
        for (int r = 0; r < 4; ++r) {
            int row = rbase + r;
            if (row < M) outp[(size_t)row * NH + colg] = (f16)(acc[t][r] + bv);
        }
    }
}

// ---------------------------------------------------------------------------
// One diffusion step in fp16 (R7-proven structure):
// hout = (xc + alpha * (A_hat h)) / (1+alpha)
// One wave per node. C=128: 16 lanes/row, 4 edge-groups, 4-deep unroll.
//                    C=64 :  8 lanes/row, 8 edge-groups, 2-deep unroll.
// FINAL: fuse "+ lin" and write fp32 to fout (layer-3 last step).
// ---------------------------------------------------------------------------
template <int C, bool FINAL>
__global__ __launch_bounds__(256) void diffuse16_kernel(
    const __half* __restrict__ h, const __half* __restrict__ xc,
    const float* __restrict__ dinv, const int* __restrict__ row_off,
    const unsigned int* __restrict__ csre, __half* __restrict__ hout,
    const f16* __restrict__ lin, float* __restrict__ fout, int N) {
    const float inv = 1.0f / (1.0f + ALPHA_C);
    int gid = blockIdx.x * blockDim.x + threadIdx.x;
    int node = gid >> 6;
    if (node >= N) return;
    int lane = threadIdx.x & 63;
    float di = dinv[node];
    float di2 = di * di;
    int e0 = row_off[node], e1 = row_off[node + 1];

    if constexpr (C == 128) {
        int l = lane & 15, grp = lane >> 4;
        float acc[8];
#pragma unroll
        for (int i = 0; i < 8; ++i) acc[i] = 0.f;
        size_t coff = (size_t)l * 8;

        if (grp == 0) {  // analytic self-loop
            float4 rv = *(const float4*)(h + ((size_t)node << 7) + coff);
            const __half2* p = (const __half2*)&rv;
#pragma unroll
            for (int k = 0; k < 4; ++k) {
                float2 f = __half22float2(p[k]);
                acc[2 * k] += di2 * f.x;
                acc[2 * k + 1] += di2 * f.y;
            }
        }
        int e = e0 + grp;
        for (; e + 12 < e1; e += 16) {
            unsigned int ev0 = csre[e], ev1 = csre[e + 4], ev2 = csre[e + 8], ev3 = csre[e + 12];
            float4 r0 = *(const float4*)(h + ((size_t)(ev0 & 0xFFFF) << 7) + coff);
            float4 r1 = *(const float4*)(h + ((size_t)(ev1 & 0xFFFF) << 7) + coff);
            float4 r2 = *(const float4*)(h + ((size_t)(ev2 & 0xFFFF) << 7) + coff);
            float4 r3 = *(const float4*)(h + ((size_t)(ev3 & 0xFFFF) << 7) + coff);
            float w0 = __half2float(__ushort_as_half((unsigned short)(ev0 >> 16)));
            float w1 = __half2float(__ushort_as_half((unsigned short)(ev1 >> 16)));
            float w2 = __half2float(__ushort_as_half((unsigned short)(ev2 >> 16)));
            float w3 = __half2float(__ushort_as_half((unsigned short)(ev3 >> 16)));
            const __half2* p0 = (const __half2*)&r0;
            const __half2* p1 = (const __half2*)&r1;
            const __half2* p2 = (const __half2*)&r2;
            const __half2* p3 = (const __half2*)&r3;
#pragma unroll
            for (int k = 0; k < 4; ++k) {
                float2 f0 = __half22float2(p0[k]);
                float2 f1 = __half22float2(p1[k]);
                float2 f2 = __half22float2(p2[k]);
                float2 f3 = __half22float2(p3[k]);
                acc[2 * k]     += w0 * f0.x + w1 * f1.x + w2 * f2.x + w3 * f3.x;
                acc[2 * k + 1] += w0 * f0.y + w1 * f1.y + w2 * f2.y + w3 * f3.y;
            }
        }
        for (; e < e1; e += 4) {
            unsigned int ev0 = csre[e];
            float4 r0 = *(const float4*)(h + ((size_t)(ev0 & 0xFFFF) << 7) + coff);
            float w0 = __half2float(__ushort_as_half((unsigned short)(ev0 >> 16)));
            const __half2* p0 = (const __half2*)&r0;
#pragma unroll
            for (int k = 0; k < 4; ++k) {
                float2 f0 = __half22float2(p0[k]);
                acc[2 * k]     += w0 * f0.x;
                acc[2 * k + 1] += w0 * f0.y;
            }
        }
#pragma unroll
        for (int i = 0; i < 8; ++i) {
            acc[i] += __shfl_xor(acc[i], 16);
            acc[i] += __shfl_xor(acc[i], 32);
        }
        if (grp == 0) {
            float4 xv = *(const float4*)(xc + ((size_t)node << 7) + coff);
            const __half2* xp = (const __half2*)&xv;
            __half ov[8];
#pragma unroll
            for (int k = 0; k < 4; ++k) {
                float2 xf = __half22float2(xp[k]);
                ov[2 * k]     = __float2half((xf.x + ALPHA_C * acc[2 * k]) * inv);
                ov[2 * k + 1] = __float2half((xf.y + ALPHA_C * acc[2 * k + 1]) * inv);
            }
            *(float4*)(hout + ((size_t)node << 7) + coff) = *(float4*)ov;
        }
    } else {  // C == 64: 8 lanes per row, 8 edge-groups
        int l = lane & 7, grp = lane >> 3;
        float acc[8];
#pragma unroll
        for (int i = 0; i < 8; ++i) acc[i] = 0.f;
        size_t coff = (size_t)l * 8;

        if (grp == 0) {
            float4 rv = *(const float4*)(h + ((size_t)node << 6) + coff);
            const __half2* p = (const __half2*)&rv;
#pragma unroll
            for (int k = 0; k < 4; ++k) {
                float2 f = __half22float2(p[k]);
                acc[2 * k] += di2 * f.x;
                acc[2 * k + 1] += di2 * f.y;
            }
        }
        int e = e0 + grp;
        for (; e + 8 < e1; e += 16) {
            unsigned int ev0 = csre[e], ev1 = csre[e + 8];
            float4 r0 = *(const float4*)(h + ((size_t)(ev0 & 0xFFFF) << 6) + coff);
            float4 r1 = *(const float4*)(h + ((size_t)(ev1 & 0xFFFF) << 6) + coff);
            float w0 = __half2float(__ushort_as_half((unsigned short)(ev0 >> 16)));
            float w1 = __half2float(__ushort_as_half((unsigned short)(ev1 >> 16)));
            const __half2* p0 = (const __half2*)&r0;
            const __half2* p1 = (const __half2*)&r1;
#pragma unroll
            for (int k = 0; k < 4; ++k) {
                float2 f0 = __half22float2(p0[k]);
                float2 f1 = __half22float2(p1[k]);
                acc[2 * k]     += w0 * f0.x + w1 * f1.x;
                acc[2 * k + 1] += w0 * f0.y + w1 * f1.y;
            }
        }
        if (e < e1) {
            unsigned int ev0 = csre[e];
            float4 r0 = *(const float4*)(h + ((size_t)(ev0 & 0xFFFF) << 6) + coff);
            float w0 = __half2float(__ushort_as_half((unsigned short)(ev0 >> 16)));
            const __half2* p0 = (const __half2*)&r0;
#pragma unroll
            for (int k = 0; k < 4; ++k) {
                float2 f0 = __half22float2(p0[k]);
                acc[2 * k]     += w0 * f0.x;
                acc[2 * k + 1] += w0 * f0.y;
            }
        }
#pragma unroll
        for (int i = 0; i < 8; ++i) {
            acc[i] += __shfl_xor(acc[i], 8);
            acc[i] += __shfl_xor(acc[i], 16);
            acc[i] += __shfl_xor(acc[i], 32);
        }
        if (grp == 0) {
            float4 xv = *(const float4*)(xc + ((size_t)node << 6) + coff);
            const __half2* xp = (const __half2*)&xv;
            float r[8];
#pragma unroll
            for (int k = 0; k < 4; ++k) {
                float2 xf = __half22float2(xp[k]);
                r[2 * k]     = (xf.x + ALPHA_C * acc[2 * k]) * inv;
                r[2 * k + 1] = (xf.y + ALPHA_C * acc[2 * k + 1]) * inv;
            }
            if constexpr (FINAL) {
                f16x8 lv = *(const f16x8*)(lin + ((size_t)node << 6) + coff);
                float4 o0, o1;
                o0.x = r[0] + (float)lv[0]; o0.y = r[1] + (float)lv[1];
                o0.z = r[2] + (float)lv[2]; o0.w = r[3] + (float)lv[3];
                o1.x = r[4] + (float)lv[4]; o1.y = r[5] + (float)lv[5];
                o1.z = r[6] + (float)lv[6]; o1.w = r[7] + (float)lv[7];
                float* op = fout + ((size_t)node << 6) + coff;
                *(float4*)op = o0;
                *(float4*)(op + 4) = o1;
            } else {
                __half ov[8];
#pragma unroll
                for (int k = 0; k < 8; ++k) ov[k] = __float2half(r[k]);
                *(float4*)(hout + ((size_t)node << 6) + coff) = *(float4*)ov;
            }
        }
    }
}

// ---------------------------------------------------------------------------
extern "C" void kernel_launch(void* const* d_in, const int* in_sizes, int n_in,
                              void* d_out, int out_size, void* d_ws, size_t ws_size,
                              hipStream_t stream) {
    const float* x   = (const float*)d_in[0];
    const void*  ei  = d_in[1];
    const float* Wc1 = (const float*)d_in[2];  const float* bc1 = (const float*)d_in[3];
    const float* Wl1 = (const float*)d_in[4];  const float* bl1 = (const float*)d_in[5];
    const float* Wc2 = (const float*)d_in[6];  const float* bc2 = (const float*)d_in[7];
    const float* Wl2 = (const float*)d_in[8];  const float* bl2 = (const float*)d_in[9];
    const float* Wc3 = (const float*)d_in[10]; const float* bc3 = (const float*)d_in[11];
    const float* Wl3 = (const float*)d_in[12]; const float* bl3 = (const float*)d_in[13];
    float* out = (float*)d_out;

    const int N = in_sizes[0] / 256;
    const int E = in_sizes[1] / 2;
    const int NB = (N + 63) >> 6;            // 64-node buckets (<= 1024)

    size_t off = 0;
    auto alloc = [&](size_t bytes) {
        void* p = (char*)d_ws + off;
        off += (bytes + 255) & ~(size_t)255;
        return p;
    };
    f16* x16 = (f16*)alloc((size_t)N * 256 * 2);
    f16* B0 = (f16*)alloc((size_t)N * 128 * 2);
    f16* B1 = (f16*)alloc((size_t)N * 128 * 2);
    f16* B2 = (f16*)alloc((size_t)N * 128 * 2);
    f16* B3 = (f16*)alloc((size_t)N * 128 * 2);
    f16* B4 = (f16*)alloc((size_t)N * 128 * 2);
    f16* wt1c = (f16*)alloc((size_t)256 * 128 * 2);
    f16* wt1l = (f16*)alloc((size_t)256 * 128 * 2);
    f16* wt2c = (f16*)alloc((size_t)128 * 128 * 2);
    f16* wt2l = (f16*)alloc((size_t)128 * 128 * 2);
    f16* wt3c = (f16*)alloc((size_t)128 * 64 * 2);
    f16* wt3l = (f16*)alloc((size_t)128 * 64 * 2);
    float* dinv   = (float*)alloc((size_t)N * 4);
    // flag + cnt zeroed by one memset
    int*   zreg   = (int*)  alloc((size_t)(N + 64) * 4);
    int*   flag   = zreg;
    int*   cnt    = zreg + 64;
    int*   rowoff = (int*)  alloc((size_t)(N + 1) * 4);
    int*   bsum   = (int*)  alloc(1024 * 4);
    int*   gcur   = (int*)  alloc(1024 * 4);
    unsigned int* csre = (unsigned int*)alloc((size_t)E * 4);
    unsigned int* ebuf = (unsigned int*)alloc((size_t)E * 4);
    int*   idx32  = (int*)  alloc((size_t)2 * E * 4);
    int* src32 = idx32;
    int* dst32 = idx32 + E;

    const int TB = 256;
    int ge  = (E + TB - 1) / TB;
    int g2e = (2 * E + TB - 1) / TB;
    int nb  = (N + 255) / 256;

    hipMemsetAsync(zreg, 0, (size_t)(N + 64) * 4, stream);

    // --- x fp32 -> fp16 (streaming) ---
    int gx8 = (N * 256 / 8 + TB - 1) / TB;
    f32_to_f16_kernel<<<gx8, TB, 0, stream>>>(x, x16, N * 256 / 8);

    // --- edge index normalization + degree count (fused) ---
    detect_idx_kernel<<<ge, TB, 0, stream>>>(ei, flag, E, N);
    convert_count_kernel<<<g2e, TB, 0, stream>>>(ei, flag, idx32, cnt, E, 2 * E);

    // --- CSR build: scan, bucket-sort, coalesced finalize ---
    block_reduce_kernel<<<nb, 256, 0, stream>>>(cnt, bsum, dinv, N);
    scan_top_kernel<<<1, 1024, 0, stream>>>(bsum, nb);
    scan_fill_kernel<<<nb, 256, 0, stream>>>(cnt, bsum, rowoff, gcur, N);
    int gbk = (E + 8191) / 8192;
    bucket_scatter_kernel<<<gbk, 256, 0, stream>>>(src32, dst32, gcur, ebuf, E, NB);
    csr_finalize_kernel<<<NB, 256, 0, stream>>>(ebuf, rowoff, dinv, csre, N);

    // --- weight prep (one dispatch) ---
    prep_all_w_kernel<<<(114688 + TB - 1) / TB, TB, 0, stream>>>(
        Wc1, Wl1, Wc2, Wl2, Wc3, Wl3, wt1c, wt1l, wt2c, wt2l, wt3c, wt3l);

    dim3 gm((N + 63) / 64, 2);              // BM=64, SPLIT=2
    int gd = (N * 64 + TB - 1) / TB;

    // ---------------- layer 1 (256 -> 128), A = fp16 x16 ----------------
    gemm2_kernel<256, 128, 0, 2><<<gm, TB, 0, stream>>>(x16, nullptr, wt1c, wt1l, bc1, bl1, B0, B1, N);
    diffuse16_kernel<128, false><<<gd, TB, 0, stream>>>((__half*)B0, (__half*)B0, dinv, rowoff, csre, (__half*)B2, nullptr, nullptr, N);
    diffuse16_kernel<128, false><<<gd, TB, 0, stream>>>((__half*)B2, (__half*)B0, dinv, rowoff, csre, (__half*)B3, nullptr, nullptr, N);
    diffuse16_kernel<128, false><<<gd, TB, 0, stream>>>((__half*)B3, (__half*)B0, dinv, rowoff, csre, (__half*)B2, nullptr, nullptr, N);
    diffuse16_kernel<128, false><<<gd, TB, 0, stream>>>((__half*)B2, (__half*)B0, dinv, rowoff, csre, (__half*)B3, nullptr, nullptr, N);

    // ---------------- layer 2 (128 -> 128), A = elu(B3 + B1) fused ----------------
    gemm2_kernel<128, 128, 2, 2><<<gm, TB, 0, stream>>>(B3, B1, wt2c, wt2l, bc2, bl2, B0, B4, N);
    diffuse16_kernel<128, false><<<gd, TB, 0, stream>>>((__half*)B0, (__half*)B0, dinv, rowoff, csre, (__half*)B1, nullptr, nullptr, N);
    diffuse16_kernel<128, false><<<gd, TB, 0, stream>>>((__half*)B1, (__half*)B0, dinv, rowoff, csre, (__half*)B2, nullptr, nullptr, N);
    diffuse16_kernel<128, false><<<gd, TB, 0, stream>>>((__half*)B2, (__half*)B0, dinv, rowoff, csre, (__half*)B1, nullptr, nullptr, N);
    diffuse16_kernel<128, false><<<gd, TB, 0, stream>>>((__half*)B1, (__half*)B0, dinv, rowoff, csre, (__half*)B2, nullptr, nullptr, N);

    // ---------------- layer 3 (128 -> 64), A = elu(B2 + B4) fused ----------------
    gemm2_kernel<128, 64, 2, 2><<<gm, TB, 0, stream>>>(B2, B4, wt3c, wt3l, bc3, bl3, B0, B1, N);
    diffuse16_kernel<64, false><<<gd, TB, 0, stream>>>((__half*)B0, (__half*)B0, dinv, rowoff, csre, (__half*)B2, nullptr, nullptr, N);
    diffuse16_kernel<64, false><<<gd, TB, 0, stream>>>((__half*)B2, (__half*)B0, dinv, rowoff, csre, (__half*)B3, nullptr, nullptr, N);
    diffuse16_kernel<64, false><<<gd, TB, 0, stream>>>((__half*)B3, (__half*)B0, dinv, rowoff, csre, (__half*)B2, nullptr, nullptr, N);
    diffuse16_kernel<64, true ><<<gd, TB, 0, stream>>>((__half*)B2, (__half*)B0, dinv, rowoff, csre, nullptr, B1, out, N);
}

// Round 14
// 546.203 us; speedup vs baseline: 1.0661x; 1.0661x over previous
//
#include <hip/hip_runtime.h>
#include <hip/hip_fp16.h>
#include <math.h>

#define ALPHA_C 0.6f

typedef _Float16 f16;
typedef f16 f16x8 __attribute__((ext_vector_type(8)));
typedef float f32x4 __attribute__((ext_vector_type(4)));

// ---------------------------------------------------------------------------
// x fp32 -> fp16, pure streaming.
// ---------------------------------------------------------------------------
__global__ void f32_to_f16_kernel(const float* __restrict__ in, f16* __restrict__ out, int n8) {
    int i = blockIdx.x * blockDim.x + threadIdx.x;
    if (i >= n8) return;
    float4 a = ((const float4*)in)[2 * i];
    float4 b = ((const float4*)in)[2 * i + 1];
    f16x8 o;
    o[0] = (f16)a.x; o[1] = (f16)a.y; o[2] = (f16)a.z; o[3] = (f16)a.w;
    o[4] = (f16)b.x; o[5] = (f16)b.y; o[6] = (f16)b.z; o[7] = (f16)b.w;
    ((f16x8*)out)[i] = o;
}

// ---------------------------------------------------------------------------
// Edge-index dtype detection (int64 reference vs int32 harness doc).
// ---------------------------------------------------------------------------
__global__ void detect_idx_kernel(const void* __restrict__ ei, int* __restrict__ flag,
                                  int E, int N) {
    int i = blockIdx.x * blockDim.x + threadIdx.x;
    if (i >= E) return;
    long long v = ((const long long*)ei)[i];
    if (v < 0 || v >= (long long)N) *flag = 1;  // -> data is int32
}

// convert to int32 AND count destination degrees in one pass
__global__ void convert_count_kernel(const void* __restrict__ ei, const int* __restrict__ flag,
                                     int* __restrict__ out, int* __restrict__ cnt,
                                     int E, int n2e) {
    int i = blockIdx.x * blockDim.x + threadIdx.x;
    if (i >= n2e) return;
    int v;
    if (*flag == 0)
        v = (int)((const long long*)ei)[i];   // int64 source
    else
        v = ((const int*)ei)[i];              // already int32
    out[i] = v;
    if (i >= E) atomicAdd(&cnt[v], 1);        // dst half
}

// --- hierarchical exclusive scan: reduce (+dinv) -> top scan -> fill -------
__global__ void block_reduce_kernel(const int* __restrict__ cnt, int* __restrict__ bsum,
                                    float* __restrict__ dinv, int n) {
    __shared__ int s[256];
    int tid = threadIdx.x;
    int i = blockIdx.x * 256 + tid;
    int v = (i < n) ? cnt[i] : 0;
    if (i < n) dinv[i] = rsqrtf((float)v + 1.0f);   // +1 self-loop
    s[tid] = v;
    __syncthreads();
    for (int o = 128; o > 0; o >>= 1) {
        if (tid < o) s[tid] += s[tid + o];
        __syncthreads();
    }
    if (tid == 0) bsum[blockIdx.x] = s[0];
}

__global__ void scan_top_kernel(int* __restrict__ bsum, int nb) {
    __shared__ int s[1024];
    int tid = threadIdx.x;
    int v = (tid < nb) ? bsum[tid] : 0;
    s[tid] = v;
    __syncthreads();
    for (int o = 1; o < 1024; o <<= 1) {
        int t = (tid >= o) ? s[tid - o] : 0;
        __syncthreads();
        s[tid] += t;
        __syncthreads();
    }
    if (tid < nb) bsum[tid] = s[tid] - v;   // exclusive
}

// row_off build; ALSO seeds gcur[b] = row_off[256*b] (bucket write cursors)
__global__ void scan_fill_kernel(const int* __restrict__ cnt, const int* __restrict__ bsum,
                                 int* __restrict__ row_off, int* __restrict__ gcur, int n) {
    __shared__ int s[256];
    int tid = threadIdx.x;
    int i = blockIdx.x * 256 + tid;
    int v = (i < n) ? cnt[i] : 0;
    s[tid] = v;
    __syncthreads();
    for (int o = 1; o < 256; o <<= 1) {
        int t = (tid >= o) ? s[tid - o] : 0;
        __syncthreads();
        s[tid] += t;
        __syncthreads();
    }
    int base = bsum[blockIdx.x];
    if (i < n) {
        int ro = base + s[tid] - v;
        row_off[i] = ro;
        if ((i & 255) == 0) gcur[i >> 8] = ro;
    }
    if (i == n - 1) row_off[n] = base + s[tid];
}

// ---------------------------------------------------------------------------
// Bucket scatter v2: group edges by dst>>8 (256-node buckets) into ebuf
// (pair = src | dst<<16). CHUNK=2048 edges/block -> ~391 blocks; 12KB LDS.
// Copy-out is DENSE over the compacted LDS buffer: thread i derives its
// bucket from the entry itself, so consecutive threads in a bucket run write
// consecutive global addresses (wave-coalesced).
// ---------------------------------------------------------------------------
__global__ __launch_bounds__(256) void bucket_scatter_kernel(
    const int* __restrict__ src, const int* __restrict__ dst,
    int* __restrict__ gcur, unsigned int* __restrict__ ebuf, int E, int NB) {
    __shared__ int hist[256];
    __shared__ int loff[256];     // inclusive scan of hist
    __shared__ int lbase[256];    // global base per bucket (this block's run)
    __shared__ int lcur[256];
    __shared__ unsigned int lbuf[2048];
    int tid = threadIdx.x;
    int e0 = blockIdx.x * 2048;
    int ecnt = E - e0; if (ecnt > 2048) ecnt = 2048;

    hist[tid] = 0; lcur[tid] = 0;
    __syncthreads();
    for (int i = tid; i < ecnt; i += 256)
        atomicAdd(&hist[(unsigned)dst[e0 + i] >> 8], 1);
    __syncthreads();
    loff[tid] = hist[tid];
    __syncthreads();
    for (int o = 1; o < 256; o <<= 1) {
        int v = (tid >= o) ? loff[tid - o] : 0;
        __syncthreads();
        loff[tid] += v;
        __syncthreads();
    }
    {
        int h = hist[tid];
        lbase[tid] = (tid < NB && h) ? atomicAdd(&gcur[tid], h) : 0;
    }
    __syncthreads();
    for (int i = tid; i < ecnt; i += 256) {
        int d = dst[e0 + i], s = src[e0 + i];
        int b = (unsigned)d >> 8;
        int p = atomicAdd(&lcur[b], 1);
        lbuf[loff[b] - hist[b] + p] = (unsigned)s | ((unsigned)d << 16);
    }
    __syncthreads();
    // dense, run-coalesced copy-out
    for (int i = tid; i < ecnt; i += 256) {
        unsigned int pr = lbuf[i];
        int b = (pr >> 16) >> 8;
        int rel = i - (loff[b] - hist[b]);
        ebuf[lbase[b] + rel] = pr;
    }
}

// ---------------------------------------------------------------------------
// CSR finalize v2: one block per 256-node bucket. Read the bucket's
// contiguous ebuf range, place entries at exact CSR positions in LDS
// (per-node cursors), then stream to csre fully coalesced.
// Fallback to direct scatter if bucket exceeds LDS cap (adversarial only).
// csre entry = src:u16 | fp16(w)<<16.
// ---------------------------------------------------------------------------
__global__ __launch_bounds__(256) void csr_finalize_kernel(
    const unsigned int* __restrict__ ebuf, const int* __restrict__ row_off,
    const float* __restrict__ dinv, unsigned int* __restrict__ csre, int N) {
    __shared__ int lcur[256];
    __shared__ unsigned int lbuf[6144];
    int b = blockIdx.x;
    int n0 = b * 256;
    int n1 = n0 + 256; if (n1 > N) n1 = N;
    int base = row_off[n0];
    int cnt = row_off[n1] - base;
    int tid = threadIdx.x;
    lcur[tid] = 0;
    __syncthreads();
    bool fits = (cnt <= 6144);
    for (int i = tid; i < cnt; i += 256) {
        unsigned int pr = ebuf[base + i];
        int s = pr & 0xFFFF;
        int d = pr >> 16;
        float w = dinv[s] * dinv[d];
        unsigned int entry = (unsigned)s |
                             ((unsigned)__half_as_ushort(__float2half(w)) << 16);
        int rel = row_off[d] - base;
        int p = atomicAdd(&lcur[d - n0], 1);
        if (fits) lbuf[rel + p] = entry;
        else      csre[base + rel + p] = entry;
    }
    __syncthreads();
    if (fits)
        for (int i = tid; i < cnt; i += 256) csre[base + i] = lbuf[i];
}

// ---------------------------------------------------------------------------
// Weight prep: all six W[K][N] fp32 -> Wt[N][K] fp16, one dispatch.
// ---------------------------------------------------------------------------
__global__ void prep_all_w_kernel(
    const float* __restrict__ Wc1, const float* __restrict__ Wl1,
    const float* __restrict__ Wc2, const float* __restrict__ Wl2,
    const float* __restrict__ Wc3, const float* __restrict__ Wl3,
    f16* __restrict__ w1c, f16* __restrict__ w1l,
    f16* __restrict__ w2c, f16* __restrict__ w2l,
    f16* __restrict__ w3c, f16* __restrict__ w3l) {
    int i = blockIdx.x * blockDim.x + threadIdx.x;
    const float* W; f16* O; int K, Nn, base;
    if      (i <  32768) { W = Wc1; O = w1c; K = 256; Nn = 128; base = i; }
    else if (i <  65536) { W = Wl1; O = w1l; K = 256; Nn = 128; base = i - 32768; }
    else if (i <  81920) { W = Wc2; O = w2c; K = 128; Nn = 128; base = i - 65536; }
    else if (i <  98304) { W = Wl2; O = w2l; K = 128; Nn = 128; base = i - 81920; }
    else if (i < 106496) { W = Wc3; O = w3c; K = 128; Nn = 64;  base = i - 98304; }
    else if (i < 114688) { W = Wl3; O = w3l; K = 128; Nn = 64;  base = i - 106496; }
    else return;
    int k = base / Nn, n = base - k * Nn;
    O[(size_t)n * K + k] = (f16)W[base];
}

// ---------------------------------------------------------------------------
// MFMA GEMM v6 (R12): A row-share hoisted to registers; W in fragment-layout
// LDS (conflict-free contiguous 1KB reads); BM=64, SPLIT column-split.
// AMODE: 0 = A f16 [M][K]; 2 = A = elu(A0+A1), both f16.
// mfma_f32_16x16x32_f16; C/D: col=lane&15, row=(lane>>4)*4+reg (m89/m91).
// ---------------------------------------------------------------------------
template <int K, int NH, int AMODE, int SPLIT>
__global__ __launch_bounds__(256) void gemm2_kernel(
    const void* __restrict__ A0v, const void* __restrict__ A1v,
    const f16* __restrict__ WtA, const f16* __restrict__ WtB,
    const float* __restrict__ biasA, const float* __restrict__ biasB,
    f16* __restrict__ CA, f16* __restrict__ CB, int M) {
    constexpr int NT = 2 * NH / 16;
    constexpr int NTS = NT / SPLIT;
    constexpr int KS = K / 32;
    __shared__ f16 Wlds[NTS * 1024];

    int tid = threadIdx.x;
    int wv = tid >> 6, lane = tid & 63;
    int lr = lane & 15, lhi = lane >> 4;
    int m0 = blockIdx.x * 64;
    int tg0 = blockIdx.y * NTS;

    f32x4 acc[NTS];
#pragma unroll
    for (int t = 0; t < NTS; ++t) acc[t] = (f32x4){0.f, 0.f, 0.f, 0.f};

    int arow = m0 + wv * 16 + lr;
    int arow_c = arow < M ? arow : M - 1;
    size_t aoff = (size_t)arow_c * K + lhi * 8;

    f16x8 a[KS];
#pragma unroll
    for (int j = 0; j < KS; ++j) {
        size_t idx = aoff + j * 32;
        if constexpr (AMODE == 0) {
            a[j] = *(const f16x8*)((const f16*)A0v + idx);
        } else {
            f16x8 u0 = *(const f16x8*)((const f16*)A0v + idx);
            f16x8 u1 = *(const f16x8*)((const f16*)A1v + idx);
            f16x8 v;
#pragma unroll
            for (int jj = 0; jj < 8; ++jj) {
                float tt = (float)u0[jj] + (float)u1[jj];
                v[jj] = (f16)(tt > 0.f ? tt : expm1f(tt));
            }
            a[j] = v;
        }
    }

#pragma unroll
    for (int k0 = 0; k0 < K; k0 += 64) {
        for (int c = tid; c < NTS * 128; c += 256) {
            int tl = c >> 7;
            int rem = c & 127;
            int ks = rem >> 6, kh = (rem >> 4) & 3, r = rem & 15;
            int tg = tg0 + tl;
            int nloc = (tg < NT / 2) ? tg : tg - NT / 2;
            const f16* srcp = ((tg < NT / 2) ? WtA : WtB)
                              + (size_t)(nloc * 16 + r) * K + k0 + ks * 32 + kh * 8;
            *(f16x8*)&Wlds[(size_t)c * 8] = *(const f16x8*)srcp;
        }
        __syncthreads();

#pragma unroll
        for (int s2 = 0; s2 < 2; ++s2) {
#pragma unroll
            for (int t = 0; t < NTS; ++t) {
                f16x8 b = *(const f16x8*)&Wlds[(size_t)(t * 128 + s2 * 64 + lane) * 8];
                acc[t] = __builtin_amdgcn_mfma_f32_16x16x32_f16(a[k0 / 32 + s2], b, acc[t], 0, 0, 0);
            }
        }
        __syncthreads();
    }

    int rbase = m0 + wv * 16 + lhi * 4;
#pragma unroll
    for (int t = 0; t < NTS; ++t) {
        int tg = tg0 + t;
        bool isA = (tg < NT / 2);
        int colg = (isA ? tg : tg - NT / 2) * 16 + lr;
        f16* outp = isA ? CA : CB;
        float bv = (isA ? biasA : biasB)[colg];
#pragma unroll
        for (int r = 0; r < 4; ++r) {
            int row = rbase + r;
            if (row < M) outp[(size_t)row * NH + colg] = (f16)(acc[t][r] + bv);
        }
    }
}

// ---------------------------------------------------------------------------
// One diffusion step in fp16 (R7-proven structure):
// hout = (xc + alpha * (A_hat h)) / (1+alpha)
// One wave per node. C=128: 16 lanes/row, 4 edge-groups, 4-deep unroll.
//                    C=64 :  8 lanes/row, 8 edge-groups, 2-deep unroll.
// FINAL: fuse "+ lin" and write fp32 to fout (layer-3 last step).
// ---------------------------------------------------------------------------
template <int C, bool FINAL>
__global__ __launch_bounds__(256) void diffuse16_kernel(
    const __half* __restrict__ h, const __half* __restrict__ xc,
    const float* __restrict__ dinv, const int* __restrict__ row_off,
    const unsigned int* __restrict__ csre, __half* __restrict__ hout,
    const f16* __restrict__ lin, float* __restrict__ fout, int N) {
    const float inv = 1.0f / (1.0f + ALPHA_C);
    int gid = blockIdx.x * blockDim.x + threadIdx.x;
    int node = gid >> 6;
    if (node >= N) return;
    int lane = threadIdx.x & 63;
    float di = dinv[node];
    float di2 = di * di;
    int e0 = row_off[node], e1 = row_off[node + 1];

    if constexpr (C == 128) {
        int l = lane & 15, grp = lane >> 4;
        float acc[8];
#pragma unroll
        for (int i = 0; i < 8; ++i) acc[i] = 0.f;
        size_t coff = (size_t)l * 8;

        if (grp == 0) {  // analytic self-loop
            float4 rv = *(const float4*)(h + ((size_t)node << 7) + coff);
            const __half2* p = (const __half2*)&rv;
#pragma unroll
            for (int k = 0; k < 4; ++k) {
                float2 f = __half22float2(p[k]);
                acc[2 * k] += di2 * f.x;
                acc[2 * k + 1] += di2 * f.y;
            }
        }
        int e = e0 + grp;
        for (; e + 12 < e1; e += 16) {
            unsigned int ev0 = csre[e], ev1 = csre[e + 4], ev2 = csre[e + 8], ev3 = csre[e + 12];
            float4 r0 = *(const float4*)(h + ((size_t)(ev0 & 0xFFFF) << 7) + coff);
            float4 r1 = *(const float4*)(h + ((size_t)(ev1 & 0xFFFF) << 7) + coff);
            float4 r2 = *(const float4*)(h + ((size_t)(ev2 & 0xFFFF) << 7) + coff);
            float4 r3 = *(const float4*)(h + ((size_t)(ev3 & 0xFFFF) << 7) + coff);
            float w0 = __half2float(__ushort_as_half((unsigned short)(ev0 >> 16)));
            float w1 = __half2float(__ushort_as_half((unsigned short)(ev1 >> 16)));
            float w2 = __half2float(__ushort_as_half((unsigned short)(ev2 >> 16)));
            float w3 = __half2float(__ushort_as_half((unsigned short)(ev3 >> 16)));
            const __half2* p0 = (const __half2*)&r0;
            const __half2* p1 = (const __half2*)&r1;
            const __half2* p2 = (const __half2*)&r2;
            const __half2* p3 = (const __half2*)&r3;
#pragma unroll
            for (int k = 0; k < 4; ++k) {
                float2 f0 = __half22float2(p0[k]);
                float2 f1 = __half22float2(p1[k]);
                float2 f2 = __half22float2(p2[k]);
                float2 f3 = __half22float2(p3[k]);
                acc[2 * k]     += w0 * f0.x + w1 * f1.x + w2 * f2.x + w3 * f3.x;
                acc[2 * k + 1] += w0 * f0.y + w1 * f1.y + w2 * f2.y + w3 * f3.y;
            }
        }
        for (; e < e1; e += 4) {
            unsigned int ev0 = csre[e];
            float4 r0 = *(const float4*)(h + ((size_t)(ev0 & 0xFFFF) << 7) + coff);
            float w0 = __half2float(__ushort_as_half((unsigned short)(ev0 >> 16)));
            const __half2* p0 = (const __half2*)&r0;
#pragma unroll
            for (int k = 0; k < 4; ++k) {
                float2 f0 = __half22float2(p0[k]);
                acc[2 * k]     += w0 * f0.x;
                acc[2 * k + 1] += w0 * f0.y;
            }
        }
#pragma unroll
        for (int i = 0; i < 8; ++i) {
            acc[i] += __shfl_xor(acc[i], 16);
            acc[i] += __shfl_xor(acc[i], 32);
        }
        if (grp == 0) {
            float4 xv = *(const float4*)(xc + ((size_t)node << 7) + coff);
            const __half2* xp = (const __half2*)&xv;
            __half ov[8];
#pragma unroll
            for (int k = 0; k < 4; ++k) {
                float2 xf = __half22float2(xp[k]);
                ov[2 * k]     = __float2half((xf.x + ALPHA_C * acc[2 * k]) * inv);
                ov[2 * k + 1] = __float2half((xf.y + ALPHA_C * acc[2 * k + 1]) * inv);
            }
            *(float4*)(hout + ((size_t)node << 7) + coff) = *(float4*)ov;
        }
    } else {  // C == 64: 8 lanes per row, 8 edge-groups
        int l = lane & 7, grp = lane >> 3;
        float acc[8];
#pragma unroll
        for (int i = 0; i < 8; ++i) acc[i] = 0.f;
        size_t coff = (size_t)l * 8;

        if (grp == 0) {
            float4 rv = *(const float4*)(h + ((size_t)node << 6) + coff);
            const __half2* p = (const __half2*)&rv;
#pragma unroll
            for (int k = 0; k < 4; ++k) {
                float2 f = __half22float2(p[k]);
                acc[2 * k] += di2 * f.x;
                acc[2 * k + 1] += di2 * f.y;
            }
        }
        int e = e0 + grp;
        for (; e + 8 < e1; e += 16) {
            unsigned int ev0 = csre[e], ev1 = csre[e + 8];
            float4 r0 = *(const float4*)(h + ((size_t)(ev0 & 0xFFFF) << 6) + coff);
            float4 r1 = *(const float4*)(h + ((size_t)(ev1 & 0xFFFF) << 6) + coff);
            float w0 = __half2float(__ushort_as_half((unsigned short)(ev0 >> 16)));
            float w1 = __half2float(__ushort_as_half((unsigned short)(ev1 >> 16)));
            const __half2* p0 = (const __half2*)&r0;
            const __half2* p1 = (const __half2*)&r1;
#pragma unroll
            for (int k = 0; k < 4; ++k) {
                float2 f0 = __half22float2(p0[k]);
                float2 f1 = __half22float2(p1[k]);
                acc[2 * k]     += w0 * f0.x + w1 * f1.x;
                acc[2 * k + 1] += w0 * f0.y + w1 * f1.y;
            }
        }
        if (e < e1) {
            unsigned int ev0 = csre[e];
            float4 r0 = *(const float4*)(h + ((size_t)(ev0 & 0xFFFF) << 6) + coff);
            float w0 = __half2float(__ushort_as_half((unsigned short)(ev0 >> 16)));
            const __half2* p0 = (const __half2*)&r0;
#pragma unroll
            for (int k = 0; k < 4; ++k) {
                float2 f0 = __half22float2(p0[k]);
                acc[2 * k]     += w0 * f0.x;
                acc[2 * k + 1] += w0 * f0.y;
            }
        }
#pragma unroll
        for (int i = 0; i < 8; ++i) {
            acc[i] += __shfl_xor(acc[i], 8);
            acc[i] += __shfl_xor(acc[i], 16);
            acc[i] += __shfl_xor(acc[i], 32);
        }
        if (grp == 0) {
            float4 xv = *(const float4*)(xc + ((size_t)node << 6) + coff);
            const __half2* xp = (const __half2*)&xv;
            float r[8];
#pragma unroll
            for (int k = 0; k < 4; ++k) {
                float2 xf = __half22float2(xp[k]);
                r[2 * k]     = (xf.x + ALPHA_C * acc[2 * k]) * inv;
                r[2 * k + 1] = (xf.y + ALPHA_C * acc[2 * k + 1]) * inv;
            }
            if constexpr (FINAL) {
                f16x8 lv = *(const f16x8*)(lin + ((size_t)node << 6) + coff);
                float4 o0, o1;
                o0.x = r[0] + (float)lv[0]; o0.y = r[1] + (float)lv[1];
                o0.z = r[2] + (float)lv[2]; o0.w = r[3] + (float)lv[3];
                o1.x = r[4] + (float)lv[4]; o1.y = r[5] + (float)lv[5];
                o1.z = r[6] + (float)lv[6]; o1.w = r[7] + (float)lv[7];
                float* op = fout + ((size_t)node << 6) + coff;
                *(float4*)op = o0;
                *(float4*)(op + 4) = o1;
            } else {
                __half ov[8];
#pragma unroll
                for (int k = 0; k < 8; ++k) ov[k] = __float2half(r[k]);
                *(float4*)(hout + ((size_t)node << 6) + coff) = *(float4*)ov;
            }
        }
    }
}

// ---------------------------------------------------------------------------
extern "C" void kernel_launch(void* const* d_in, const int* in_sizes, int n_in,
                              void* d_out, int out_size, void* d_ws, size_t ws_size,
                              hipStream_t stream) {
    const float* x   = (const float*)d_in[0];
    const void*  ei  = d_in[1];
    const float* Wc1 = (const float*)d_in[2];  const float* bc1 = (const float*)d_in[3];
    const float* Wl1 = (const float*)d_in[4];  const float* bl1 = (const float*)d_in[5];
    const float* Wc2 = (const float*)d_in[6];  const float* bc2 = (const float*)d_in[7];
    const float* Wl2 = (const float*)d_in[8];  const float* bl2 = (const float*)d_in[9];
    const float* Wc3 = (const float*)d_in[10]; const float* bc3 = (const float*)d_in[11];
    const float* Wl3 = (const float*)d_in[12]; const float* bl3 = (const float*)d_in[13];
    float* out = (float*)d_out;

    const int N = in_sizes[0] / 256;
    const int E = in_sizes[1] / 2;
    const int NB = (N + 255) >> 8;           // 256-node buckets (<= 256)

    size_t off = 0;
    auto alloc = [&](size_t bytes) {
        void* p = (char*)d_ws + off;
        off += (bytes + 255) & ~(size_t)255;
        return p;
    };
    f16* x16 = (f16*)alloc((size_t)N * 256 * 2);
    f16* B0 = (f16*)alloc((size_t)N * 128 * 2);
    f16* B1 = (f16*)alloc((size_t)N * 128 * 2);
    f16* B2 = (f16*)alloc((size_t)N * 128 * 2);
    f16* B3 = (f16*)alloc((size_t)N * 128 * 2);
    f16* B4 = (f16*)alloc((size_t)N * 128 * 2);
    f16* wt1c = (f16*)alloc((size_t)256 * 128 * 2);
    f16* wt1l = (f16*)alloc((size_t)256 * 128 * 2);
    f16* wt2c = (f16*)alloc((size_t)128 * 128 * 2);
    f16* wt2l = (f16*)alloc((size_t)128 * 128 * 2);
    f16* wt3c = (f16*)alloc((size_t)128 * 64 * 2);
    f16* wt3l = (f16*)alloc((size_t)128 * 64 * 2);
    float* dinv   = (float*)alloc((size_t)N * 4);
    int*   zreg   = (int*)  alloc((size_t)(N + 64) * 4);
    int*   flag   = zreg;
    int*   cnt    = zreg + 64;
    int*   rowoff = (int*)  alloc((size_t)(N + 1) * 4);
    int*   bsum   = (int*)  alloc(1024 * 4);
    int*   gcur   = (int*)  alloc(1024 * 4);
    unsigned int* csre = (unsigned int*)alloc((size_t)E * 4);
    unsigned int* ebuf = (unsigned int*)alloc((size_t)E * 4);
    int*   idx32  = (int*)  alloc((size_t)2 * E * 4);
    int* src32 = idx32;
    int* dst32 = idx32 + E;

    const int TB = 256;
    int ge  = (E + TB - 1) / TB;
    int g2e = (2 * E + TB - 1) / TB;
    int nb  = (N + 255) / 256;

    hipMemsetAsync(zreg, 0, (size_t)(N + 64) * 4, stream);

    // --- x fp32 -> fp16 (streaming) ---
    int gx8 = (N * 256 / 8 + TB - 1) / TB;
    f32_to_f16_kernel<<<gx8, TB, 0, stream>>>(x, x16, N * 256 / 8);

    // --- edge index normalization + degree count (fused) ---
    detect_idx_kernel<<<ge, TB, 0, stream>>>(ei, flag, E, N);
    convert_count_kernel<<<g2e, TB, 0, stream>>>(ei, flag, idx32, cnt, E, 2 * E);

    // --- CSR build: scan, bucket-sort (256-node buckets), coalesced finalize ---
    block_reduce_kernel<<<nb, 256, 0, stream>>>(cnt, bsum, dinv, N);
    scan_top_kernel<<<1, 1024, 0, stream>>>(bsum, nb);
    scan_fill_kernel<<<nb, 256, 0, stream>>>(cnt, bsum, rowoff, gcur, N);
    int gbk = (E + 2047) / 2048;
    bucket_scatter_kernel<<<gbk, 256, 0, stream>>>(src32, dst32, gcur, ebuf, E, NB);
    csr_finalize_kernel<<<NB, 256, 0, stream>>>(ebuf, rowoff, dinv, csre, N);

    // --- weight prep (one dispatch) ---
    prep_all_w_kernel<<<(114688 + TB - 1) / TB, TB, 0, stream>>>(
        Wc1, Wl1, Wc2, Wl2, Wc3, Wl3, wt1c, wt1l, wt2c, wt2l, wt3c, wt3l);

    dim3 gm((N + 63) / 64, 2);              // BM=64, SPLIT=2
    int gd = (N * 64 + TB - 1) / TB;

    // ---------------- layer 1 (256 -> 128), A = fp16 x16 ----------------
    gemm2_kernel<256, 128, 0, 2><<<gm, TB, 0, stream>>>(x16, nullptr, wt1c, wt1l, bc1, bl1, B0, B1, N);
    diffuse16_kernel<128, false><<<gd, TB, 0, stream>>>((__half*)B0, (__half*)B0, dinv, rowoff, csre, (__half*)B2, nullptr, nullptr, N);
    diffuse16_kernel<128, false><<<gd, TB, 0, stream>>>((__half*)B2, (__half*)B0, dinv, rowoff, csre, (__half*)B3, nullptr, nullptr, N);
    diffuse16_kernel<128, false><<<gd, TB, 0, stream>>>((__half*)B3, (__half*)B0, dinv, rowoff, csre, (__half*)B2, nullptr, nullptr, N);
    diffuse16_kernel<128, false><<<gd, TB, 0, stream>>>((__half*)B2, (__half*)B0, dinv, rowoff, csre, (__half*)B3, nullptr, nullptr, N);

    // ---------------- layer 2 (128 -> 128), A = elu(B3 + B1) fused ----------------
    gemm2_kernel<128, 128, 2, 2><<<gm, TB, 0, stream>>>(B3, B1, wt2c, wt2l, bc2, bl2, B0, B4, N);
    diffuse16_kernel<128, false><<<gd, TB, 0, stream>>>((__half*)B0, (__half*)B0, dinv, rowoff, csre, (__half*)B1, nullptr, nullptr, N);
    diffuse16_kernel<128, false><<<gd, TB, 0, stream>>>((__half*)B1, (__half*)B0, dinv, rowoff, csre, (__half*)B2, nullptr, nullptr, N);
    diffuse16_kernel<128, false><<<gd, TB, 0, stream>>>((__half*)B2, (__half*)B0, dinv, rowoff, csre, (__half*)B1, nullptr, nullptr, N);
    diffuse16_kernel<128, false><<<gd, TB, 0, stream>>>((__half*)B1, (__half*)B0, dinv, rowoff, csre, (__half*)B2, nullptr, nullptr, N);

    // ---------------- layer 3 (128 -> 64), A = elu(B2 + B4) fused ----------------
    gemm2_kernel<128, 64, 2, 2><<<gm, TB, 0, stream>>>(B2, B4, wt3c, wt3l, bc3, bl3, B0, B1, N);
    diffuse16_kernel<64, false><<<gd, TB, 0, stream>>>((__half*)B0, (__half*)B0, dinv, rowoff, csre, (__half*)B2, nullptr, nullptr, N);
    diffuse16_kernel<64, false><<<gd, TB, 0, stream>>>((__half*)B2, (__half*)B0, dinv, rowoff, csre, (__half*)B3, nullptr, nullptr, N);
    diffuse16_kernel<64, false><<<gd, TB, 0, stream>>>((__half*)B3, (__half*)B0, dinv, rowoff, csre, (__half*)B2, nullptr, nullptr, N);
    diffuse16_kernel<64, true ><<<gd, TB, 0, stream>>>((__half*)B2, (__half*)B0, dinv, rowoff, csre, nullptr, B1, out, N);
}

// Round 15
// 521.049 us; speedup vs baseline: 1.1176x; 1.0483x over previous
//
#include <hip/hip_runtime.h>
#include <hip/hip_fp16.h>
#include <math.h>

#define ALPHA_C 0.6f

typedef _Float16 f16;
typedef f16 f16x8 __attribute__((ext_vector_type(8)));
typedef float f32x4 __attribute__((ext_vector_type(4)));

// ---------------------------------------------------------------------------
// x fp32 -> fp16, pure streaming.
// ---------------------------------------------------------------------------
__global__ void f32_to_f16_kernel(const float* __restrict__ in, f16* __restrict__ out, int n8) {
    int i = blockIdx.x * blockDim.x + threadIdx.x;
    if (i >= n8) return;
    float4 a = ((const float4*)in)[2 * i];
    float4 b = ((const float4*)in)[2 * i + 1];
    f16x8 o;
    o[0] = (f16)a.x; o[1] = (f16)a.y; o[2] = (f16)a.z; o[3] = (f16)a.w;
    o[4] = (f16)b.x; o[5] = (f16)b.y; o[6] = (f16)b.z; o[7] = (f16)b.w;
    ((f16x8*)out)[i] = o;
}

// ---------------------------------------------------------------------------
// Edge-index dtype detection (int64 reference vs int32 harness doc).
// ---------------------------------------------------------------------------
__global__ void detect_idx_kernel(const void* __restrict__ ei, int* __restrict__ flag,
                                  int E, int N) {
    int i = blockIdx.x * blockDim.x + threadIdx.x;
    if (i >= E) return;
    long long v = ((const long long*)ei)[i];
    if (v < 0 || v >= (long long)N) *flag = 1;  // -> data is int32
}

// convert to int32 + per-block LDS histogram of dst 256-node buckets.
// Flush = 256 atomics/block to 256 hot counters (vs 800k random per-node).
__global__ __launch_bounds__(256) void convert_hist_kernel(
    const void* __restrict__ ei, const int* __restrict__ flag,
    int* __restrict__ out, int* __restrict__ bcnt, int E, int n2e) {
    __shared__ int hist[256];
    int tid = threadIdx.x;
    hist[tid] = 0;
    __syncthreads();
    bool is64 = (*flag == 0);
    for (int i = blockIdx.x * 256 + tid; i < n2e; i += gridDim.x * 256) {
        int v = is64 ? (int)((const long long*)ei)[i] : ((const int*)ei)[i];
        out[i] = v;
        if (i >= E) atomicAdd(&hist[(unsigned)v >> 8], 1);
    }
    __syncthreads();
    int h = hist[tid];
    if (h) atomicAdd(&bcnt[tid], h);
}

// exclusive scan of NB (<=256) bucket counts -> boff[0..NB], gcur seed
__global__ void bucket_scan_kernel(const int* __restrict__ bcnt, int* __restrict__ boff,
                                   int* __restrict__ gcur, int NB) {
    __shared__ int s[256];
    int tid = threadIdx.x;
    int v = (tid < NB) ? bcnt[tid] : 0;
    s[tid] = v;
    __syncthreads();
    for (int o = 1; o < 256; o <<= 1) {
        int t = (tid >= o) ? s[tid - o] : 0;
        __syncthreads();
        s[tid] += t;
        __syncthreads();
    }
    int ex = s[tid] - v;
    if (tid < NB) { boff[tid] = ex; gcur[tid] = ex; }
    if (tid == NB - 1) boff[NB] = ex + v;
}

// ---------------------------------------------------------------------------
// Bucket scatter (R14): group edges by dst>>8 into ebuf (pair = src|dst<<16).
// CHUNK=2048 edges/block; dense run-coalesced copy-out.
// ---------------------------------------------------------------------------
__global__ __launch_bounds__(256) void bucket_scatter_kernel(
    const int* __restrict__ src, const int* __restrict__ dst,
    int* __restrict__ gcur, unsigned int* __restrict__ ebuf, int E, int NB) {
    __shared__ int hist[256];
    __shared__ int loff[256];
    __shared__ int lbase[256];
    __shared__ int lcur[256];
    __shared__ unsigned int lbuf[2048];
    int tid = threadIdx.x;
    int e0 = blockIdx.x * 2048;
    int ecnt = E - e0; if (ecnt > 2048) ecnt = 2048;

    hist[tid] = 0; lcur[tid] = 0;
    __syncthreads();
    for (int i = tid; i < ecnt; i += 256)
        atomicAdd(&hist[(unsigned)dst[e0 + i] >> 8], 1);
    __syncthreads();
    loff[tid] = hist[tid];
    __syncthreads();
    for (int o = 1; o < 256; o <<= 1) {
        int v = (tid >= o) ? loff[tid - o] : 0;
        __syncthreads();
        loff[tid] += v;
        __syncthreads();
    }
    {
        int h = hist[tid];
        lbase[tid] = (tid < NB && h) ? atomicAdd(&gcur[tid], h) : 0;
    }
    __syncthreads();
    for (int i = tid; i < ecnt; i += 256) {
        int d = dst[e0 + i], s = src[e0 + i];
        int b = (unsigned)d >> 8;
        int p = atomicAdd(&lcur[b], 1);
        lbuf[loff[b] - hist[b] + p] = (unsigned)s | ((unsigned)d << 16);
    }
    __syncthreads();
    for (int i = tid; i < ecnt; i += 256) {
        unsigned int pr = lbuf[i];
        int b = (pr >> 16) >> 8;
        int rel = i - (loff[b] - hist[b]);
        ebuf[lbase[b] + rel] = pr;
    }
}

// ---------------------------------------------------------------------------
// finalize_a: per 256-node bucket, per-node degree count from the bucket's
// contiguous ebuf run (LDS) + 256-scan -> writes row_off and dinv.
// Replaces the N-wide count/scan pipeline and its 800k random atomics.
// ---------------------------------------------------------------------------
__global__ __launch_bounds__(256) void finalize_a_kernel(
    const unsigned int* __restrict__ ebuf, const int* __restrict__ boff,
    int* __restrict__ row_off, float* __restrict__ dinv, int N) {
    __shared__ int ncnt[256];
    __shared__ int ps[256];
    int b = blockIdx.x;
    int n0 = b << 8;
    int base = boff[b];
    int cnt = boff[b + 1] - base;
    int tid = threadIdx.x;
    ncnt[tid] = 0;
    __syncthreads();
    for (int i = tid; i < cnt; i += 256)
        atomicAdd(&ncnt[(int)(ebuf[base + i] >> 16) - n0], 1);
    __syncthreads();
    int v = ncnt[tid];
    ps[tid] = v;
    __syncthreads();
    for (int o = 1; o < 256; o <<= 1) {
        int t = (tid >= o) ? ps[tid - o] : 0;
        __syncthreads();
        ps[tid] += t;
        __syncthreads();
    }
    int node = n0 + tid;
    if (node < N) {
        row_off[node] = base + ps[tid] - v;
        dinv[node] = rsqrtf((float)v + 1.0f);   // +1 self-loop
        if (node == N - 1) row_off[N] = base + ps[tid];
    }
}

// ---------------------------------------------------------------------------
// CSR finalize (R14): place entries at exact CSR positions in LDS, stream
// to csre fully coalesced. csre entry = src:u16 | fp16(w)<<16.
// ---------------------------------------------------------------------------
__global__ __launch_bounds__(256) void csr_finalize_kernel(
    const unsigned int* __restrict__ ebuf, const int* __restrict__ row_off,
    const float* __restrict__ dinv, unsigned int* __restrict__ csre, int N) {
    __shared__ int lcur[256];
    __shared__ unsigned int lbuf[6144];
    int b = blockIdx.x;
    int n0 = b * 256;
    int n1 = n0 + 256; if (n1 > N) n1 = N;
    int base = row_off[n0];
    int cnt = row_off[n1] - base;
    int tid = threadIdx.x;
    lcur[tid] = 0;
    __syncthreads();
    bool fits = (cnt <= 6144);
    for (int i = tid; i < cnt; i += 256) {
        unsigned int pr = ebuf[base + i];
        int s = pr & 0xFFFF;
        int d = pr >> 16;
        float w = dinv[s] * dinv[d];
        unsigned int entry = (unsigned)s |
                             ((unsigned)__half_as_ushort(__float2half(w)) << 16);
        int rel = row_off[d] - base;
        int p = atomicAdd(&lcur[d - n0], 1);
        if (fits) lbuf[rel + p] = entry;
        else      csre[base + rel + p] = entry;
    }
    __syncthreads();
    if (fits)
        for (int i = tid; i < cnt; i += 256) csre[base + i] = lbuf[i];
}

// ---------------------------------------------------------------------------
// Weight prep: all six W[K][N] fp32 -> Wt[N][K] fp16, one dispatch.
// ---------------------------------------------------------------------------
__global__ void prep_all_w_kernel(
    const float* __restrict__ Wc1, const float* __restrict__ Wl1,
    const float* __restrict__ Wc2, const float* __restrict__ Wl2,
    const float* __restrict__ Wc3, const float* __restrict__ Wl3,
    f16* __restrict__ w1c, f16* __restrict__ w1l,
    f16* __restrict__ w2c, f16* __restrict__ w2l,
    f16* __restrict__ w3c, f16* __restrict__ w3l) {
    int i = blockIdx.x * blockDim.x + threadIdx.x;
    const float* W; f16* O; int K, Nn, base;
    if      (i <  32768) { W = Wc1; O = w1c; K = 256; Nn = 128; base = i; }
    else if (i <  65536) { W = Wl1; O = w1l; K = 256; Nn = 128; base = i - 32768; }
    else if (i <  81920) { W = Wc2; O = w2c; K = 128; Nn = 128; base = i - 65536; }
    else if (i <  98304) { W = Wl2; O = w2l; K = 128; Nn = 128; base = i - 81920; }
    else if (i < 106496) { W = Wc3; O = w3c; K = 128; Nn = 64;  base = i - 98304; }
    else if (i < 114688) { W = Wl3; O = w3l; K = 128; Nn = 64;  base = i - 106496; }
    else return;
    int k = base / Nn, n = base - k * Nn;
    O[(size_t)n * K + k] = (f16)W[base];
}

// ---------------------------------------------------------------------------
// MFMA GEMM v6 (R12): A row-share hoisted to registers; W in fragment-layout
// LDS (conflict-free contiguous 1KB reads); BM=64, SPLIT column-split.
// AMODE: 0 = A f16 [M][K]; 2 = A = elu(A0+A1), both f16.
// mfma_f32_16x16x32_f16; C/D: col=lane&15, row=(lane>>4)*4+reg (m89/m91).
// ---------------------------------------------------------------------------
template <int K, int NH, int AMODE, int SPLIT>
__global__ __launch_bounds__(256) void gemm2_kernel(
    const void* __restrict__ A0v, const void* __restrict__ A1v,
    const f16* __restrict__ WtA, const f16* __restrict__ WtB,
    const float* __restrict__ biasA, const float* __restrict__ biasB,
    f16* __restrict__ CA, f16* __restrict__ CB, int M) {
    constexpr int NT = 2 * NH / 16;
    constexpr int NTS = NT / SPLIT;
    constexpr int KS = K / 32;
    __shared__ f16 Wlds[NTS * 1024];

    int tid = threadIdx.x;
    int wv = tid >> 6, lane = tid & 63;
    int lr = lane & 15, lhi = lane >> 4;
    int m0 = blockIdx.x * 64;
    int tg0 = blockIdx.y * NTS;

    f32x4 acc[NTS];
#pragma unroll
    for (int t = 0; t < NTS; ++t) acc[t] = (f32x4){0.f, 0.f, 0.f, 0.f};

    int arow = m0 + wv * 16 + lr;
    int arow_c = arow < M ? arow : M - 1;
    size_t aoff = (size_t)arow_c * K + lhi * 8;

    f16x8 a[KS];
#pragma unroll
    for (int j = 0; j < KS; ++j) {
        size_t idx = aoff + j * 32;
        if constexpr (AMODE == 0) {
            a[j] = *(const f16x8*)((const f16*)A0v + idx);
        } else {
            f16x8 u0 = *(const f16x8*)((const f16*)A0v + idx);
            f16x8 u1 = *(const f16x8*)((const f16*)A1v + idx);
            f16x8 v;
#pragma unroll
            for (int jj = 0; jj < 8; ++jj) {
                float tt = (float)u0[jj] + (float)u1[jj];
                v[jj] = (f16)(tt > 0.f ? tt : expm1f(tt));
            }
            a[j] = v;
        }
    }

#pragma unroll
    for (int k0 = 0; k0 < K; k0 += 64) {
        for (int c = tid; c < NTS * 128; c += 256) {
            int tl = c >> 7;
            int rem = c & 127;
            int ks = rem >> 6, kh = (rem >> 4) & 3, r = rem & 15;
            int tg = tg0 + tl;
            int nloc = (tg < NT / 2) ? tg : tg - NT / 2;
            const f16* srcp = ((tg < NT / 2) ? WtA : WtB)
                              + (size_t)(nloc * 16 + r) * K + k0 + ks * 32 + kh * 8;
            *(f16x8*)&Wlds[(size_t)c * 8] = *(const f16x8*)srcp;
        }
        __syncthreads();

#pragma unroll
        for (int s2 = 0; s2 < 2; ++s2) {
#pragma unroll
            for (int t = 0; t < NTS; ++t) {
                f16x8 b = *(const f16x8*)&Wlds[(size_t)(t * 128 + s2 * 64 + lane) * 8];
                acc[t] = __builtin_amdgcn_mfma_f32_16x16x32_f16(a[k0 / 32 + s2], b, acc[t], 0, 0, 0);
            }
        }
        __syncthreads();
    }

    int rbase = m0 + wv * 16 + lhi * 4;
#pragma unroll
    for (int t = 0; t < NTS; ++t) {
        int tg = tg0 + t;
        bool isA = (tg < NT / 2);
        int colg = (isA ? tg : tg - NT / 2) * 16 + lr;
        f16* outp = isA ? CA : CB;
        float bv = (isA ? biasA : biasB)[colg];
#pragma unroll
        for (int r = 0; r < 4; ++r) {
            int row = rbase + r;
            if (row < M) outp[(size_t)row * NH + colg] = (f16)(acc[t][r] + bv);
        }
    }
}

// ---------------------------------------------------------------------------
// One diffusion step in fp16 (R7-proven structure):
// hout = (xc + alpha * (A_hat h)) / (1+alpha)
// One wave per node. C=128: 16 lanes/row, 4 edge-groups, 4-deep unroll.
//                    C=64 :  8 lanes/row, 8 edge-groups, 2-deep unroll.
// FINAL: fuse "+ lin" and write fp32 to fout (layer-3 last step).
// ---------------------------------------------------------------------------
template <int C, bool FINAL>
__global__ __launch_bounds__(256) void diffuse16_kernel(
    const __half* __restrict__ h, const __half* __restrict__ xc,
    const float* __restrict__ dinv, const int* __restrict__ row_off,
    const unsigned int* __restrict__ csre, __half* __restrict__ hout,
    const f16* __restrict__ lin, float* __restrict__ fout, int N) {
    const float inv = 1.0f / (1.0f + ALPHA_C);
    int gid = blockIdx.x * blockDim.x + threadIdx.x;
    int node = gid >> 6;
    if (node >= N) return;
    int lane = threadIdx.x & 63;
    float di = dinv[node];
    float di2 = di * di;
    int e0 = row_off[node], e1 = row_off[node + 1];

    if constexpr (C == 128) {
        int l = lane & 15, grp = lane >> 4;
        float acc[8];
#pragma unroll
        for (int i = 0; i < 8; ++i) acc[i] = 0.f;
        size_t coff = (size_t)l * 8;

        if (grp == 0) {  // analytic self-loop
            float4 rv = *(const float4*)(h + ((size_t)node << 7) + coff);
            const __half2* p = (const __half2*)&rv;
#pragma unroll
            for (int k = 0; k < 4; ++k) {
                float2 f = __half22float2(p[k]);
                acc[2 * k] += di2 * f.x;
                acc[2 * k + 1] += di2 * f.y;
            }
        }
        int e = e0 + grp;
        for (; e + 12 < e1; e += 16) {
            unsigned int ev0 = csre[e], ev1 = csre[e + 4], ev2 = csre[e + 8], ev3 = csre[e + 12];
            float4 r0 = *(const float4*)(h + ((size_t)(ev0 & 0xFFFF) << 7) + coff);
            float4 r1 = *(const float4*)(h + ((size_t)(ev1 & 0xFFFF) << 7) + coff);
            float4 r2 = *(const float4*)(h + ((size_t)(ev2 & 0xFFFF) << 7) + coff);
            float4 r3 = *(const float4*)(h + ((size_t)(ev3 & 0xFFFF) << 7) + coff);
            float w0 = __half2float(__ushort_as_half((unsigned short)(ev0 >> 16)));
            float w1 = __half2float(__ushort_as_half((unsigned short)(ev1 >> 16)));
            float w2 = __half2float(__ushort_as_half((unsigned short)(ev2 >> 16)));
            float w3 = __half2float(__ushort_as_half((unsigned short)(ev3 >> 16)));
            const __half2* p0 = (const __half2*)&r0;
            const __half2* p1 = (const __half2*)&r1;
            const __half2* p2 = (const __half2*)&r2;
            const __half2* p3 = (const __half2*)&r3;
#pragma unroll
            for (int k = 0; k < 4; ++k) {
                float2 f0 = __half22float2(p0[k]);
                float2 f1 = __half22float2(p1[k]);
                float2 f2 = __half22float2(p2[k]);
                float2 f3 = __half22float2(p3[k]);
                acc[2 * k]     += w0 * f0.x + w1 * f1.x + w2 * f2.x + w3 * f3.x;
                acc[2 * k + 1] += w0 * f0.y + w1 * f1.y + w2 * f2.y + w3 * f3.y;
            }
        }
        for (; e < e1; e += 4) {
            unsigned int ev0 = csre[e];
            float4 r0 = *(const float4*)(h + ((size_t)(ev0 & 0xFFFF) << 7) + coff);
            float w0 = __half2float(__ushort_as_half((unsigned short)(ev0 >> 16)));
            const __half2* p0 = (const __half2*)&r0;
#pragma unroll
            for (int k = 0; k < 4; ++k) {
                float2 f0 = __half22float2(p0[k]);
                acc[2 * k]     += w0 * f0.x;
                acc[2 * k + 1] += w0 * f0.y;
            }
        }
#pragma unroll
        for (int i = 0; i < 8; ++i) {
            acc[i] += __shfl_xor(acc[i], 16);
            acc[i] += __shfl_xor(acc[i], 32);
        }
        if (grp == 0) {
            float4 xv = *(const float4*)(xc + ((size_t)node << 7) + coff);
            const __half2* xp = (const __half2*)&xv;
            __half ov[8];
#pragma unroll
            for (int k = 0; k < 4; ++k) {
                float2 xf = __half22float2(xp[k]);
                ov[2 * k]     = __float2half((xf.x + ALPHA_C * acc[2 * k]) * inv);
                ov[2 * k + 1] = __float2half((xf.y + ALPHA_C * acc[2 * k + 1]) * inv);
            }
            *(float4*)(hout + ((size_t)node << 7) + coff) = *(float4*)ov;
        }
    } else {  // C == 64: 8 lanes per row, 8 edge-groups
        int l = lane & 7, grp = lane >> 3;
        float acc[8];
#pragma unroll
        for (int i = 0; i < 8; ++i) acc[i] = 0.f;
        size_t coff = (size_t)l * 8;

        if (grp == 0) {
            float4 rv = *(const float4*)(h + ((size_t)node << 6) + coff);
            const __half2* p = (const __half2*)&rv;
#pragma unroll
            for (int k = 0; k < 4; ++k) {
                float2 f = __half22float2(p[k]);
                acc[2 * k] += di2 * f.x;
                acc[2 * k + 1] += di2 * f.y;
            }
        }
        int e = e0 + grp;
        for (; e + 8 < e1; e += 16) {
            unsigned int ev0 = csre[e], ev1 = csre[e + 8];
            float4 r0 = *(const float4*)(h + ((size_t)(ev0 & 0xFFFF) << 6) + coff);
            float4 r1 = *(const float4*)(h + ((size_t)(ev1 & 0xFFFF) << 6) + coff);
            float w0 = __half2float(__ushort_as_half((unsigned short)(ev0 >> 16)));
            float w1 = __half2float(__ushort_as_half((unsigned short)(ev1 >> 16)));
            const __half2* p0 = (const __half2*)&r0;
            const __half2* p1 = (const __half2*)&r1;
#pragma unroll
            for (int k = 0; k < 4; ++k) {
                float2 f0 = __half22float2(p0[k]);
                float2 f1 = __half22float2(p1[k]);
                acc[2 * k]     += w0 * f0.x + w1 * f1.x;
                acc[2 * k + 1] += w0 * f0.y + w1 * f1.y;
            }
        }
        if (e < e1) {
            unsigned int ev0 = csre[e];
            float4 r0 = *(const float4*)(h + ((size_t)(ev0 & 0xFFFF) << 6) + coff);
            float w0 = __half2float(__ushort_as_half((unsigned short)(ev0 >> 16)));
            const __half2* p0 = (const __half2*)&r0;
#pragma unroll
            for (int k = 0; k < 4; ++k) {
                float2 f0 = __half22float2(p0[k]);
                acc[2 * k]     += w0 * f0.x;
                acc[2 * k + 1] += w0 * f0.y;
            }
        }
#pragma unroll
        for (int i = 0; i < 8; ++i) {
            acc[i] += __shfl_xor(acc[i], 8);
            acc[i] += __shfl_xor(acc[i], 16);
            acc[i] += __shfl_xor(acc[i], 32);
        }
        if (grp == 0) {
            float4 xv = *(const float4*)(xc + ((size_t)node << 6) + coff);
            const __half2* xp = (const __half2*)&xv;
            float r[8];
#pragma unroll
            for (int k = 0; k < 4; ++k) {
                float2 xf = __half22float2(xp[k]);
                r[2 * k]     = (xf.x + ALPHA_C * acc[2 * k]) * inv;
                r[2 * k + 1] = (xf.y + ALPHA_C * acc[2 * k + 1]) * inv;
            }
            if constexpr (FINAL) {
                f16x8 lv = *(const f16x8*)(lin + ((size_t)node << 6) + coff);
                float4 o0, o1;
                o0.x = r[0] + (float)lv[0]; o0.y = r[1] + (float)lv[1];
                o0.z = r[2] + (float)lv[2]; o0.w = r[3] + (float)lv[3];
                o1.x = r[4] + (float)lv[4]; o1.y = r[5] + (float)lv[5];
                o1.z = r[6] + (float)lv[6]; o1.w = r[7] + (float)lv[7];
                float* op = fout + ((size_t)node << 6) + coff;
                *(float4*)op = o0;
                *(float4*)(op + 4) = o1;
            } else {
                __half ov[8];
#pragma unroll
                for (int k = 0; k < 8; ++k) ov[k] = __float2half(r[k]);
                *(float4*)(hout + ((size_t)node << 6) + coff) = *(float4*)ov;
            }
        }
    }
}

// ---------------------------------------------------------------------------
extern "C" void kernel_launch(void* const* d_in, const int* in_sizes, int n_in,
                              void* d_out, int out_size, void* d_ws, size_t ws_size,
                              hipStream_t stream) {
    const float* x   = (const float*)d_in[0];
    const void*  ei  = d_in[1];
    const float* Wc1 = (const float*)d_in[2];  const float* bc1 = (const float*)d_in[3];
    const float* Wl1 = (const float*)d_in[4];  const float* bl1 = (const float*)d_in[5];
    const float* Wc2 = (const float*)d_in[6];  const float* bc2 = (const float*)d_in[7];
    const float* Wl2 = (const float*)d_in[8];  const float* bl2 = (const float*)d_in[9];
    const float* Wc3 = (const float*)d_in[10]; const float* bc3 = (const float*)d_in[11];
    const float* Wl3 = (const float*)d_in[12]; const float* bl3 = (const float*)d_in[13];
    float* out = (float*)d_out;

    const int N = in_sizes[0] / 256;
    const int E = in_sizes[1] / 2;
    const int NB = (N + 255) >> 8;           // 256-node buckets (<= 256)

    size_t off = 0;
    auto alloc = [&](size_t bytes) {
        void* p = (char*)d_ws + off;
        off += (bytes + 255) & ~(size_t)255;
        return p;
    };
    f16* x16 = (f16*)alloc((size_t)N * 256 * 2);
    f16* B0 = (f16*)alloc((size_t)N * 128 * 2);
    f16* B1 = (f16*)alloc((size_t)N * 128 * 2);
    f16* B2 = (f16*)alloc((size_t)N * 128 * 2);
    f16* B3 = (f16*)alloc((size_t)N * 128 * 2);
    f16* B4 = (f16*)alloc((size_t)N * 128 * 2);
    f16* wt1c = (f16*)alloc((size_t)256 * 128 * 2);
    f16* wt1l = (f16*)alloc((size_t)256 * 128 * 2);
    f16* wt2c = (f16*)alloc((size_t)128 * 128 * 2);
    f16* wt2l = (f16*)alloc((size_t)128 * 128 * 2);
    f16* wt3c = (f16*)alloc((size_t)128 * 64 * 2);
    f16* wt3l = (f16*)alloc((size_t)128 * 64 * 2);
    float* dinv   = (float*)alloc((size_t)N * 4);
    int*   zreg   = (int*)  alloc((size_t)(64 + 256) * 4);  // flag + bucket counts
    int*   flag   = zreg;
    int*   bcnt   = zreg + 64;
    int*   rowoff = (int*)  alloc((size_t)(N + 1) * 4);
    int*   boff   = (int*)  alloc(257 * 4);
    int*   gcur   = (int*)  alloc(256 * 4);
    unsigned int* csre = (unsigned int*)alloc((size_t)E * 4);
    unsigned int* ebuf = (unsigned int*)alloc((size_t)E * 4);
    int*   idx32  = (int*)  alloc((size_t)2 * E * 4);
    int* src32 = idx32;
    int* dst32 = idx32 + E;

    const int TB = 256;
    int ge  = (E + TB - 1) / TB;

    hipMemsetAsync(zreg, 0, (size_t)(64 + 256) * 4, stream);

    // --- x fp32 -> fp16 (streaming) ---
    int gx8 = (N * 256 / 8 + TB - 1) / TB;
    f32_to_f16_kernel<<<gx8, TB, 0, stream>>>(x, x16, N * 256 / 8);

    // --- edge index normalization + bucket histogram (fused) ---
    detect_idx_kernel<<<ge, TB, 0, stream>>>(ei, flag, E, N);
    convert_hist_kernel<<<480, TB, 0, stream>>>(ei, flag, idx32, bcnt, E, 2 * E);

    // --- CSR build: bucket scan, scatter, row_off+dinv, coalesced finalize ---
    bucket_scan_kernel<<<1, 256, 0, stream>>>(bcnt, boff, gcur, NB);
    int gbk = (E + 2047) / 2048;
    bucket_scatter_kernel<<<gbk, 256, 0, stream>>>(src32, dst32, gcur, ebuf, E, NB);
    finalize_a_kernel<<<NB, 256, 0, stream>>>(ebuf, boff, rowoff, dinv, N);
    csr_finalize_kernel<<<NB, 256, 0, stream>>>(ebuf, rowoff, dinv, csre, N);

    // --- weight prep (one dispatch) ---
    prep_all_w_kernel<<<(114688 + TB - 1) / TB, TB, 0, stream>>>(
        Wc1, Wl1, Wc2, Wl2, Wc3, Wl3, wt1c, wt1l, wt2c, wt2l, wt3c, wt3l);

    dim3 gm((N + 63) / 64, 2);              // BM=64, SPLIT=2
    int gd = (N * 64 + TB - 1) / TB;

    // ---------------- layer 1 (256 -> 128), A = fp16 x16 ----------------
    gemm2_kernel<256, 128, 0, 2><<<gm, TB, 0, stream>>>(x16, nullptr, wt1c, wt1l, bc1, bl1, B0, B1, N);
    diffuse16_kernel<128, false><<<gd, TB, 0, stream>>>((__half*)B0, (__half*)B0, dinv, rowoff, csre, (__half*)B2, nullptr, nullptr, N);
    diffuse16_kernel<128, false><<<gd, TB, 0, stream>>>((__half*)B2, (__half*)B0, dinv, rowoff, csre, (__half*)B3, nullptr, nullptr, N);
    diffuse16_kernel<128, false><<<gd, TB, 0, stream>>>((__half*)B3, (__half*)B0, dinv, rowoff, csre, (__half*)B2, nullptr, nullptr, N);
    diffuse16_kernel<128, false><<<gd, TB, 0, stream>>>((__half*)B2, (__half*)B0, dinv, rowoff, csre, (__half*)B3, nullptr, nullptr, N);

    // ---------------- layer 2 (128 -> 128), A = elu(B3 + B1) fused ----------------
    gemm2_kernel<128, 128, 2, 2><<<gm, TB, 0, stream>>>(B3, B1, wt2c, wt2l, bc2, bl2, B0, B4, N);
    diffuse16_kernel<128, false><<<gd, TB, 0, stream>>>((__half*)B0, (__half*)B0, dinv, rowoff, csre, (__half*)B1, nullptr, nullptr, N);
    diffuse16_kernel<128, false><<<gd, TB, 0, stream>>>((__half*)B1, (__half*)B0, dinv, rowoff, csre, (__half*)B2, nullptr, nullptr, N);
    diffuse16_kernel<128, false><<<gd, TB, 0, stream>>>((__half*)B2, (__half*)B0, dinv, rowoff, csre, (__half*)B1, nullptr, nullptr, N);
    diffuse16_kernel<128, false><<<gd, TB, 0, stream>>>((__half*)B1, (__half*)B0, dinv, rowoff, csre, (__half*)B2, nullptr, nullptr, N);

    // ---------------- layer 3 (128 -> 64), A = elu(B2 + B4) fused ----------------
    gemm2_kernel<128, 64, 2, 2><<<gm, TB, 0, stream>>>(B2, B4, wt3c, wt3l, bc3, bl3, B0, B1, N);
    diffuse16_kernel<64, false><<<gd, TB, 0, stream>>>((__half*)B0, (__half*)B0, dinv, rowoff, csre, (__half*)B2, nullptr, nullptr, N);
    diffuse16_kernel<64, false><<<gd, TB, 0, stream>>>((__half*)B2, (__half*)B0, dinv, rowoff, csre, (__half*)B3, nullptr, nullptr, N);
    diffuse16_kernel<64, false><<<gd, TB, 0, stream>>>((__half*)B3, (__half*)B0, dinv, rowoff, csre, (__half*)B2, nullptr, nullptr, N);
    diffuse16_kernel<64, true ><<<gd, TB, 0, stream>>>((__half*)B2, (__half*)B0, dinv, rowoff, csre, nullptr, B1, out, N);
}